// Round 1
// baseline (1735.102 us; speedup 1.0000x reference)
//
#include <hip/hip_runtime.h>
#include <math.h>

// ---------------------------------------------------------------------------
// GCN 2-layer: out = log_softmax(gcn2(relu(gcn1(x))))
// gcn(x) folded as: g[j] = dinv[j]*(x[j]@W);  out[i] = dinv[i]*(sum_{j->i} g[j] + g[i]) + b
// ---------------------------------------------------------------------------

__global__ void k_init_deg(float* __restrict__ deg, int n) {
    int i = blockIdx.x * blockDim.x + threadIdx.x;
    if (i < n) deg[i] = 1.0f;  // self-loop contributes 1 to degree
}

__global__ void k_degree(const int* __restrict__ dst, float* __restrict__ deg, int E) {
    int e = blockIdx.x * blockDim.x + threadIdx.x;
    if (e < E) atomicAdd(&deg[dst[e]], 1.0f);
}

__global__ void k_dinv(float* __restrict__ deg, int n) {
    int i = blockIdx.x * blockDim.x + threadIdx.x;
    if (i < n) deg[i] = rsqrtf(deg[i]);  // deg >= 1 always (self-loop)
}

// g1[row][c] = dinv[row] * sum_k x[row][k] * W1[k][c];  16 out cols as 4x float4
// One thread per (row, c4): 4 threads share a row (identical x addresses -> broadcast).
__global__ void k_gemm1(const float* __restrict__ x, const float* __restrict__ W1,
                        const float* __restrict__ dinv, float4* __restrict__ g1v, int n) {
    __shared__ float4 sW4[512];  // W1 [128][16] as [k][c4] float4
    int tid = threadIdx.x;
    for (int i = tid; i < 512; i += 256) sW4[i] = ((const float4*)W1)[i];
    __syncthreads();
    int idx = blockIdx.x * 256 + tid;
    int row = idx >> 2, c4 = idx & 3;
    if (row >= n) return;
    const float4* xr = (const float4*)(x + (size_t)row * 128);
    float4 acc = make_float4(0.f, 0.f, 0.f, 0.f);
    for (int q = 0; q < 32; ++q) {
        float4 xv = xr[q];
        #pragma unroll
        for (int j = 0; j < 4; ++j) {
            float s = (j == 0) ? xv.x : (j == 1) ? xv.y : (j == 2) ? xv.z : xv.w;
            float4 w = sW4[(q * 4 + j) * 4 + c4];
            acc.x += s * w.x; acc.y += s * w.y; acc.z += s * w.z; acc.w += s * w.w;
        }
    }
    float di = dinv[row];
    acc.x *= di; acc.y *= di; acc.z *= di; acc.w *= di;
    g1v[(size_t)row * 4 + c4] = acc;
}

// acc1[dst] += g1[src]  (16 floats per edge)
__global__ void k_scatter1(const int* __restrict__ src, const int* __restrict__ dst,
                           const float4* __restrict__ g1v, float* __restrict__ acc1, int E) {
    int e = blockIdx.x * blockDim.x + threadIdx.x;
    if (e >= E) return;
    int s = src[e], d = dst[e];
    float* a = acc1 + (size_t)d * 16;
    #pragma unroll
    for (int q = 0; q < 4; ++q) {
        float4 v = g1v[(size_t)s * 4 + q];
        atomicAdd(a + q * 4 + 0, v.x);
        atomicAdd(a + q * 4 + 1, v.y);
        atomicAdd(a + q * 4 + 2, v.z);
        atomicAdd(a + q * 4 + 3, v.w);
    }
}

// z = relu(dinv*(acc1+g1) + b1);  g2 = dinv * (z @ W2)   (16 -> 3)
__global__ void k_layer2(const float* __restrict__ acc1, const float* __restrict__ g1,
                         const float* __restrict__ dinv, const float* __restrict__ b1,
                         const float* __restrict__ W2, float* __restrict__ g2, int n) {
    int i = blockIdx.x * blockDim.x + threadIdx.x;
    if (i >= n) return;
    float di = dinv[i];
    const float4* a4 = (const float4*)acc1 + (size_t)i * 4;
    const float4* g4 = (const float4*)g1 + (size_t)i * 4;
    float z[16];
    #pragma unroll
    for (int q = 0; q < 4; ++q) {
        float4 a = a4[q], g = g4[q];
        z[q * 4 + 0] = fmaxf(0.f, di * (a.x + g.x) + b1[q * 4 + 0]);
        z[q * 4 + 1] = fmaxf(0.f, di * (a.y + g.y) + b1[q * 4 + 1]);
        z[q * 4 + 2] = fmaxf(0.f, di * (a.z + g.z) + b1[q * 4 + 2]);
        z[q * 4 + 3] = fmaxf(0.f, di * (a.w + g.w) + b1[q * 4 + 3]);
    }
    float o0 = 0.f, o1 = 0.f, o2 = 0.f;
    #pragma unroll
    for (int c = 0; c < 16; ++c) {
        float zc = z[c];
        o0 += zc * W2[c * 3 + 0];
        o1 += zc * W2[c * 3 + 1];
        o2 += zc * W2[c * 3 + 2];
    }
    g2[(size_t)i * 3 + 0] = di * o0;
    g2[(size_t)i * 3 + 1] = di * o1;
    g2[(size_t)i * 3 + 2] = di * o2;
}

// acc2[dst] += g2[src]  (3 floats per edge)
__global__ void k_scatter2(const int* __restrict__ src, const int* __restrict__ dst,
                           const float* __restrict__ g2, float* __restrict__ acc2, int E) {
    int e = blockIdx.x * blockDim.x + threadIdx.x;
    if (e >= E) return;
    int s = src[e], d = dst[e];
    float v0 = g2[(size_t)s * 3 + 0];
    float v1 = g2[(size_t)s * 3 + 1];
    float v2 = g2[(size_t)s * 3 + 2];
    atomicAdd(&acc2[(size_t)d * 3 + 0], v0);
    atomicAdd(&acc2[(size_t)d * 3 + 1], v1);
    atomicAdd(&acc2[(size_t)d * 3 + 2], v2);
}

// v = dinv*(acc2+g2) + b2;  out = log_softmax(v) over 3 classes
__global__ void k_final(const float* __restrict__ acc2, const float* __restrict__ g2,
                        const float* __restrict__ dinv, const float* __restrict__ b2,
                        float* __restrict__ out, int n) {
    int i = blockIdx.x * blockDim.x + threadIdx.x;
    if (i >= n) return;
    float di = dinv[i];
    float v0 = di * (acc2[(size_t)i * 3 + 0] + g2[(size_t)i * 3 + 0]) + b2[0];
    float v1 = di * (acc2[(size_t)i * 3 + 1] + g2[(size_t)i * 3 + 1]) + b2[1];
    float v2 = di * (acc2[(size_t)i * 3 + 2] + g2[(size_t)i * 3 + 2]) + b2[2];
    float m = fmaxf(v0, fmaxf(v1, v2));
    float e0 = expf(v0 - m), e1 = expf(v1 - m), e2 = expf(v2 - m);
    float lse = logf(e0 + e1 + e2);
    out[(size_t)i * 3 + 0] = v0 - m - lse;
    out[(size_t)i * 3 + 1] = v1 - m - lse;
    out[(size_t)i * 3 + 2] = v2 - m - lse;
}

extern "C" void kernel_launch(void* const* d_in, const int* in_sizes, int n_in,
                              void* d_out, int out_size, void* d_ws, size_t ws_size,
                              hipStream_t stream) {
    const float* x  = (const float*)d_in[0];
    const int*   ei = (const int*)d_in[1];      // [2][E], values < 100000
    const float* W1 = (const float*)d_in[2];    // [128][16]
    const float* b1 = (const float*)d_in[3];    // [16]
    const float* W2 = (const float*)d_in[4];    // [16][3]
    const float* b2 = (const float*)d_in[5];    // [3]
    float* out = (float*)d_out;

    const int n = in_sizes[0] / 128;            // 100000
    const int E = in_sizes[1] / 2;              // 1600000
    const int* src = ei;
    const int* dst = ei + E;

    // workspace layout (floats):
    //   deg/dinv: [0, n)   g1: [n, 17n)   acc1: [17n, 33n)   g2: [33n, 36n)   acc2: [36n, 39n)
    float* ws   = (float*)d_ws;
    float* dinv = ws;
    float* g1   = ws + (size_t)n;
    float* acc1 = ws + (size_t)17 * n;
    float* g2   = ws + (size_t)33 * n;
    float* acc2 = ws + (size_t)36 * n;

    // zero acc1, g2, acc2 in one shot ([17n, 39n))
    hipMemsetAsync(acc1, 0, (size_t)22 * n * sizeof(float), stream);

    const int B = 256;
    int gn = (n + B - 1) / B;
    int gE = (E + B - 1) / B;

    k_init_deg<<<gn, B, 0, stream>>>(dinv, n);
    k_degree<<<gE, B, 0, stream>>>(dst, dinv, E);
    k_dinv<<<gn, B, 0, stream>>>(dinv, n);
    k_gemm1<<<((size_t)n * 4 + B - 1) / B, B, 0, stream>>>(x, W1, dinv, (float4*)g1, n);
    k_scatter1<<<gE, B, 0, stream>>>(src, dst, (const float4*)g1, acc1, E);
    k_layer2<<<gn, B, 0, stream>>>(acc1, g1, dinv, b1, W2, g2, n);
    k_scatter2<<<gE, B, 0, stream>>>(src, dst, g2, acc2, E);
    k_final<<<gn, B, 0, stream>>>(acc2, g2, dinv, b2, out, n);
}

// Round 2
// 328.442 us; speedup vs baseline: 5.2828x; 5.2828x over previous
//
#include <hip/hip_runtime.h>
#include <math.h>

// ---------------------------------------------------------------------------
// GCN 2-layer via dst-ordered CSR + gather (no float atomics on the data path)
// g[j] = dinv[j]*(x[j]@W);  out[i] = dinv[i]*(sum_{j->i} g[j] + g[i]) + b
// ---------------------------------------------------------------------------

__global__ void k_count(const int* __restrict__ dst, int* __restrict__ deg, int E) {
    int e = blockIdx.x * blockDim.x + threadIdx.x;
    if (e < E) atomicAdd(&deg[dst[e]], 1);
}

__global__ void k_dinv(const int* __restrict__ deg, float* __restrict__ dinv, int n) {
    int i = blockIdx.x * blockDim.x + threadIdx.x;
    if (i < n) dinv[i] = rsqrtf((float)(deg[i] + 1));  // +1 = self-loop
}

// ---- 3-kernel exclusive prefix scan over deg[] -> row_start[] ----
__global__ void k_scan_block(const int* __restrict__ deg, int* __restrict__ bsum, int n) {
    __shared__ int s[256];
    int t = threadIdx.x;
    int i = blockIdx.x * 256 + t;
    s[t] = (i < n) ? deg[i] : 0;
    __syncthreads();
    for (int o = 128; o > 0; o >>= 1) {
        if (t < o) s[t] += s[t + o];
        __syncthreads();
    }
    if (t == 0) bsum[blockIdx.x] = s[0];
}

__global__ void k_scan_top(int* __restrict__ bsum, int nb) {  // single block, 512 threads
    __shared__ int s[512];
    int t = threadIdx.x;
    int orig = (t < nb) ? bsum[t] : 0;
    s[t] = orig;
    __syncthreads();
    for (int o = 1; o < 512; o <<= 1) {
        int add = (t >= o) ? s[t - o] : 0;
        __syncthreads();
        s[t] += add;
        __syncthreads();
    }
    if (t < nb) bsum[t] = s[t] - orig;  // exclusive
}

__global__ void k_row_start(const int* __restrict__ deg, const int* __restrict__ bsum,
                            int* __restrict__ row_start, int n) {
    __shared__ int s[256];
    int t = threadIdx.x;
    int i = blockIdx.x * 256 + t;
    int v = (i < n) ? deg[i] : 0;
    s[t] = v;
    __syncthreads();
    for (int o = 1; o < 256; o <<= 1) {
        int add = (t >= o) ? s[t - o] : 0;
        __syncthreads();
        s[t] += add;
        __syncthreads();
    }
    if (i < n) row_start[i] = bsum[blockIdx.x] + s[t] - v;  // exclusive
}

__global__ void k_fill(const int* __restrict__ src, const int* __restrict__ dst,
                       const int* __restrict__ row_start, int* __restrict__ cursor,
                       int* __restrict__ csr, int E) {
    int e = blockIdx.x * blockDim.x + threadIdx.x;
    if (e >= E) return;
    int d = dst[e];
    int p = atomicAdd(&cursor[d], 1);
    csr[row_start[d] + p] = src[e];
}

// g1[row][c] = dinv[row] * sum_k x[row][k] * W1[k][c];  4 threads per row (c4 = 0..3)
__global__ void k_gemm1(const float* __restrict__ x, const float* __restrict__ W1,
                        const float* __restrict__ dinv, float4* __restrict__ g1v, int n) {
    __shared__ float4 sW4[512];  // W1 [128][16] as [k][c4] float4
    int tid = threadIdx.x;
    for (int i = tid; i < 512; i += 256) sW4[i] = ((const float4*)W1)[i];
    __syncthreads();
    int idx = blockIdx.x * 256 + tid;
    int row = idx >> 2, c4 = idx & 3;
    if (row >= n) return;
    const float4* xr = (const float4*)(x + (size_t)row * 128);
    float4 acc = make_float4(0.f, 0.f, 0.f, 0.f);
    for (int q = 0; q < 32; ++q) {
        float4 xv = xr[q];
        #pragma unroll
        for (int j = 0; j < 4; ++j) {
            float s = (j == 0) ? xv.x : (j == 1) ? xv.y : (j == 2) ? xv.z : xv.w;
            float4 w = sW4[(q * 4 + j) * 4 + c4];
            acc.x += s * w.x; acc.y += s * w.y; acc.z += s * w.z; acc.w += s * w.w;
        }
    }
    float di = dinv[row];
    acc.x *= di; acc.y *= di; acc.z *= di; acc.w *= di;
    g1v[(size_t)row * 4 + c4] = acc;
}

// Fused: gather layer-1 messages + relu/bias + (z @ W2) -> g2 padded to float4.
// 4 threads per node, thread c4 owns features [4*c4, 4*c4+4).
__global__ void k_gather1(const float4* __restrict__ g1v, const int* __restrict__ csr,
                          const int* __restrict__ row_start, const int* __restrict__ deg,
                          const float* __restrict__ dinv, const float* __restrict__ b1,
                          const float* __restrict__ W2, float4* __restrict__ g2p, int n) {
    int idx = blockIdx.x * 256 + threadIdx.x;
    int i = idx >> 2, c4 = idx & 3;
    if (i >= n) return;
    int off = row_start[i], dg = deg[i];
    float4 acc = g1v[(size_t)i * 4 + c4];  // self-loop term
    for (int k = 0; k < dg; ++k) {
        int s = csr[off + k];
        float4 v = g1v[(size_t)s * 4 + c4];
        acc.x += v.x; acc.y += v.y; acc.z += v.z; acc.w += v.w;
    }
    float di = dinv[i];
    float z0 = fmaxf(0.f, di * acc.x + b1[c4 * 4 + 0]);
    float z1 = fmaxf(0.f, di * acc.y + b1[c4 * 4 + 1]);
    float z2 = fmaxf(0.f, di * acc.z + b1[c4 * 4 + 2]);
    float z3 = fmaxf(0.f, di * acc.w + b1[c4 * 4 + 3]);
    const float* w = W2 + c4 * 12;  // rows 4*c4 .. 4*c4+3 of [16][3]
    float o0 = z0 * w[0] + z1 * w[3] + z2 * w[6] + z3 * w[9];
    float o1 = z0 * w[1] + z1 * w[4] + z2 * w[7] + z3 * w[10];
    float o2 = z0 * w[2] + z1 * w[5] + z2 * w[8] + z3 * w[11];
    // reduce across the 4 sibling lanes (same wave: lanes differ in bits 0..1)
    o0 += __shfl_xor(o0, 1); o0 += __shfl_xor(o0, 2);
    o1 += __shfl_xor(o1, 1); o1 += __shfl_xor(o1, 2);
    o2 += __shfl_xor(o2, 1); o2 += __shfl_xor(o2, 2);
    if (c4 == 0) g2p[i] = make_float4(di * o0, di * o1, di * o2, 0.f);
}

// Fused: gather layer-2 messages + bias + log_softmax. 4 threads per node split edges.
__global__ void k_gather2(const float4* __restrict__ g2p, const int* __restrict__ csr,
                          const int* __restrict__ row_start, const int* __restrict__ deg,
                          const float* __restrict__ dinv, const float* __restrict__ b2,
                          float* __restrict__ out, int n) {
    int idx = blockIdx.x * 256 + threadIdx.x;
    int i = idx >> 2, t = idx & 3;
    if (i >= n) return;
    int off = row_start[i], dg = deg[i];
    float v0 = 0.f, v1 = 0.f, v2 = 0.f;
    for (int k = t; k < dg; k += 4) {
        int s = csr[off + k];
        float4 g = g2p[s];
        v0 += g.x; v1 += g.y; v2 += g.z;
    }
    v0 += __shfl_xor(v0, 1); v0 += __shfl_xor(v0, 2);
    v1 += __shfl_xor(v1, 1); v1 += __shfl_xor(v1, 2);
    v2 += __shfl_xor(v2, 1); v2 += __shfl_xor(v2, 2);
    if (t != 0) return;
    float4 self = g2p[i];
    float di = dinv[i];
    float a0 = di * (v0 + self.x) + b2[0];
    float a1 = di * (v1 + self.y) + b2[1];
    float a2 = di * (v2 + self.z) + b2[2];
    float m = fmaxf(a0, fmaxf(a1, a2));
    float e0 = expf(a0 - m), e1 = expf(a1 - m), e2 = expf(a2 - m);
    float lse = logf(e0 + e1 + e2);
    out[(size_t)i * 3 + 0] = a0 - m - lse;
    out[(size_t)i * 3 + 1] = a1 - m - lse;
    out[(size_t)i * 3 + 2] = a2 - m - lse;
}

extern "C" void kernel_launch(void* const* d_in, const int* in_sizes, int n_in,
                              void* d_out, int out_size, void* d_ws, size_t ws_size,
                              hipStream_t stream) {
    const float* x  = (const float*)d_in[0];
    const int*   ei = (const int*)d_in[1];      // [2][E]
    const float* W1 = (const float*)d_in[2];    // [128][16]
    const float* b1 = (const float*)d_in[3];    // [16]
    const float* W2 = (const float*)d_in[4];    // [16][3]
    const float* b2 = (const float*)d_in[5];    // [3]
    float* out = (float*)d_out;

    const int n = in_sizes[0] / 128;            // 100000
    const int E = in_sizes[1] / 2;              // 1600000
    const int* src = ei;
    const int* dst = ei + E;

    // workspace layout (all offsets 16B-aligned by construction)
    char* ws = (char*)d_ws;
    int*   deg       = (int*)ws;                          // n ints   (memset 0)
    int*   cursor    = (int*)(ws + (size_t)n * 4);        // n ints   (memset 0)
    float* dinv      = (float*)(ws + (size_t)2 * n * 4);  // n floats
    int*   row_start = (int*)(ws + (size_t)3 * n * 4);    // n ints
    int*   bsum      = (int*)(ws + (size_t)4 * n * 4);    // 512 ints
    int*   csr       = (int*)(ws + (size_t)4 * n * 4 + 2048);            // E ints
    float* g1        = (float*)(ws + (size_t)4 * n * 4 + 2048 + (size_t)E * 4);  // 16n floats
    float* g2p       = g1 + (size_t)16 * n;                              // 4n floats

    hipMemsetAsync(deg, 0, (size_t)2 * n * sizeof(int), stream);  // deg + cursor

    const int B = 256;
    int gn  = (n + B - 1) / B;          // node-grid
    int gn4 = (4 * n + B - 1) / B;      // 4-threads-per-node grid
    int gE  = (E + B - 1) / B;          // edge-grid
    int nb  = gn;                       // number of scan blocks (<= 512)

    k_count<<<gE, B, 0, stream>>>(dst, deg, E);
    k_dinv<<<gn, B, 0, stream>>>(deg, dinv, n);
    k_scan_block<<<nb, B, 0, stream>>>(deg, bsum, n);
    k_scan_top<<<1, 512, 0, stream>>>(bsum, nb);
    k_row_start<<<nb, B, 0, stream>>>(deg, bsum, row_start, n);
    k_fill<<<gE, B, 0, stream>>>(src, dst, row_start, cursor, csr, E);
    k_gemm1<<<gn4, B, 0, stream>>>(x, W1, dinv, (float4*)g1, n);
    k_gather1<<<gn4, B, 0, stream>>>((const float4*)g1, csr, row_start, deg, dinv, b1, W2,
                                     (float4*)g2p, n);
    k_gather2<<<gn4, B, 0, stream>>>((const float4*)g2p, csr, row_start, deg, dinv, b2, out, n);
}

// Round 3
// 238.787 us; speedup vs baseline: 7.2663x; 1.3755x over previous
//
#include <hip/hip_runtime.h>
#include <math.h>

// ---------------------------------------------------------------------------
// GCN 2-layer via dst-ordered CSR + gather (single atomic pass for CSR build)
// g[j] = dinv[j]*(x[j]@W);  out[i] = dinv[i]*(sum_{j->i} g[j] + g[i]) + b
// ---------------------------------------------------------------------------

// Count in-degree AND record each edge's rank within its dst row (atomic ret).
__global__ void k_count_rank(const int* __restrict__ dst, int* __restrict__ deg,
                             unsigned short* __restrict__ rank, int E) {
    int e = blockIdx.x * blockDim.x + threadIdx.x;
    if (e >= E) return;
    int d = dst[e];
    int p = atomicAdd(&deg[d], 1);
    rank[e] = (unsigned short)p;
}

// ---- 3-kernel exclusive prefix scan over deg[] -> row_start[] ----
__global__ void k_scan_block(const int* __restrict__ deg, int* __restrict__ bsum, int n) {
    __shared__ int s[256];
    int t = threadIdx.x;
    int i = blockIdx.x * 256 + t;
    s[t] = (i < n) ? deg[i] : 0;
    __syncthreads();
    for (int o = 128; o > 0; o >>= 1) {
        if (t < o) s[t] += s[t + o];
        __syncthreads();
    }
    if (t == 0) bsum[blockIdx.x] = s[0];
}

__global__ void k_scan_top(int* __restrict__ bsum, int nb) {  // single block, 512 threads
    __shared__ int s[512];
    int t = threadIdx.x;
    int orig = (t < nb) ? bsum[t] : 0;
    s[t] = orig;
    __syncthreads();
    for (int o = 1; o < 512; o <<= 1) {
        int add = (t >= o) ? s[t - o] : 0;
        __syncthreads();
        s[t] += add;
        __syncthreads();
    }
    if (t < nb) bsum[t] = s[t] - orig;  // exclusive
}

// row_start = exclusive scan of deg; also dinv = rsqrt(deg+1) (fused, reads deg anyway)
__global__ void k_row_start(const int* __restrict__ deg, const int* __restrict__ bsum,
                            int* __restrict__ row_start, float* __restrict__ dinv, int n) {
    __shared__ int s[256];
    int t = threadIdx.x;
    int i = blockIdx.x * 256 + t;
    int v = (i < n) ? deg[i] : 0;
    s[t] = v;
    __syncthreads();
    for (int o = 1; o < 256; o <<= 1) {
        int add = (t >= o) ? s[t - o] : 0;
        __syncthreads();
        s[t] += add;
        __syncthreads();
    }
    if (i < n) {
        row_start[i] = bsum[blockIdx.x] + s[t] - v;  // exclusive
        dinv[i] = rsqrtf((float)(v + 1));            // +1 = self-loop
    }
}

// Atomic-free CSR fill using precomputed ranks.
__global__ void k_fill(const int* __restrict__ src, const int* __restrict__ dst,
                       const int* __restrict__ row_start, const unsigned short* __restrict__ rank,
                       int* __restrict__ csr, int E) {
    int e = blockIdx.x * blockDim.x + threadIdx.x;
    if (e >= E) return;
    csr[row_start[dst[e]] + (int)rank[e]] = src[e];
}

// g1[row][c] = dinv[row] * sum_k x[row][k] * W1[k][c];  4 threads per row (c4 = 0..3)
__global__ void k_gemm1(const float* __restrict__ x, const float* __restrict__ W1,
                        const float* __restrict__ dinv, float4* __restrict__ g1v, int n) {
    __shared__ float4 sW4[512];  // W1 [128][16] as [k][c4] float4
    int tid = threadIdx.x;
    for (int i = tid; i < 512; i += 256) sW4[i] = ((const float4*)W1)[i];
    __syncthreads();
    int idx = blockIdx.x * 256 + tid;
    int row = idx >> 2, c4 = idx & 3;
    if (row >= n) return;
    const float4* xr = (const float4*)(x + (size_t)row * 128);
    float4 acc = make_float4(0.f, 0.f, 0.f, 0.f);
    for (int q = 0; q < 32; ++q) {
        float4 xv = xr[q];
        #pragma unroll
        for (int j = 0; j < 4; ++j) {
            float s = (j == 0) ? xv.x : (j == 1) ? xv.y : (j == 2) ? xv.z : xv.w;
            float4 w = sW4[(q * 4 + j) * 4 + c4];
            acc.x += s * w.x; acc.y += s * w.y; acc.z += s * w.z; acc.w += s * w.w;
        }
    }
    float di = dinv[row];
    acc.x *= di; acc.y *= di; acc.z *= di; acc.w *= di;
    g1v[(size_t)row * 4 + c4] = acc;
}

// Fused: gather layer-1 messages + relu/bias + (z @ W2) -> g2 padded to float4.
// 4 threads per node, thread c4 owns features [4*c4, 4*c4+4).
__global__ void k_gather1(const float4* __restrict__ g1v, const int* __restrict__ csr,
                          const int* __restrict__ row_start, const int* __restrict__ deg,
                          const float* __restrict__ dinv, const float* __restrict__ b1,
                          const float* __restrict__ W2, float4* __restrict__ g2p, int n) {
    int idx = blockIdx.x * 256 + threadIdx.x;
    int i = idx >> 2, c4 = idx & 3;
    if (i >= n) return;
    int off = row_start[i], dg = deg[i];
    float4 acc = g1v[(size_t)i * 4 + c4];  // self-loop term
    for (int k = 0; k < dg; ++k) {
        int s = csr[off + k];
        float4 v = g1v[(size_t)s * 4 + c4];
        acc.x += v.x; acc.y += v.y; acc.z += v.z; acc.w += v.w;
    }
    float di = dinv[i];
    float z0 = fmaxf(0.f, di * acc.x + b1[c4 * 4 + 0]);
    float z1 = fmaxf(0.f, di * acc.y + b1[c4 * 4 + 1]);
    float z2 = fmaxf(0.f, di * acc.z + b1[c4 * 4 + 2]);
    float z3 = fmaxf(0.f, di * acc.w + b1[c4 * 4 + 3]);
    const float* w = W2 + c4 * 12;  // rows 4*c4 .. 4*c4+3 of [16][3]
    float o0 = z0 * w[0] + z1 * w[3] + z2 * w[6] + z3 * w[9];
    float o1 = z0 * w[1] + z1 * w[4] + z2 * w[7] + z3 * w[10];
    float o2 = z0 * w[2] + z1 * w[5] + z2 * w[8] + z3 * w[11];
    // reduce across the 4 sibling lanes (same wave: lanes differ in bits 0..1)
    o0 += __shfl_xor(o0, 1); o0 += __shfl_xor(o0, 2);
    o1 += __shfl_xor(o1, 1); o1 += __shfl_xor(o1, 2);
    o2 += __shfl_xor(o2, 1); o2 += __shfl_xor(o2, 2);
    if (c4 == 0) g2p[i] = make_float4(di * o0, di * o1, di * o2, 0.f);
}

// Fused: gather layer-2 messages + bias + log_softmax. 4 threads per node split edges.
__global__ void k_gather2(const float4* __restrict__ g2p, const int* __restrict__ csr,
                          const int* __restrict__ row_start, const int* __restrict__ deg,
                          const float* __restrict__ dinv, const float* __restrict__ b2,
                          float* __restrict__ out, int n) {
    int idx = blockIdx.x * 256 + threadIdx.x;
    int i = idx >> 2, t = idx & 3;
    if (i >= n) return;
    int off = row_start[i], dg = deg[i];
    float v0 = 0.f, v1 = 0.f, v2 = 0.f;
    for (int k = t; k < dg; k += 4) {
        int s = csr[off + k];
        float4 g = g2p[s];
        v0 += g.x; v1 += g.y; v2 += g.z;
    }
    v0 += __shfl_xor(v0, 1); v0 += __shfl_xor(v0, 2);
    v1 += __shfl_xor(v1, 1); v1 += __shfl_xor(v1, 2);
    v2 += __shfl_xor(v2, 1); v2 += __shfl_xor(v2, 2);
    if (t != 0) return;
    float4 self = g2p[i];
    float di = dinv[i];
    float a0 = di * (v0 + self.x) + b2[0];
    float a1 = di * (v1 + self.y) + b2[1];
    float a2 = di * (v2 + self.z) + b2[2];
    float m = fmaxf(a0, fmaxf(a1, a2));
    float e0 = expf(a0 - m), e1 = expf(a1 - m), e2 = expf(a2 - m);
    float lse = logf(e0 + e1 + e2);
    out[(size_t)i * 3 + 0] = a0 - m - lse;
    out[(size_t)i * 3 + 1] = a1 - m - lse;
    out[(size_t)i * 3 + 2] = a2 - m - lse;
}

extern "C" void kernel_launch(void* const* d_in, const int* in_sizes, int n_in,
                              void* d_out, int out_size, void* d_ws, size_t ws_size,
                              hipStream_t stream) {
    const float* x  = (const float*)d_in[0];
    const int*   ei = (const int*)d_in[1];      // [2][E]
    const float* W1 = (const float*)d_in[2];    // [128][16]
    const float* b1 = (const float*)d_in[3];    // [16]
    const float* W2 = (const float*)d_in[4];    // [16][3]
    const float* b2 = (const float*)d_in[5];    // [3]
    float* out = (float*)d_out;

    const int n = in_sizes[0] / 128;            // 100000
    const int E = in_sizes[1] / 2;              // 1600000
    const int* src = ei;
    const int* dst = ei + E;

    // workspace layout (16B-aligned offsets)
    char* ws = (char*)d_ws;
    int*   deg       = (int*)ws;                          // n ints   (memset 0)
    float* dinv      = (float*)(ws + (size_t)n * 4);      // n floats
    int*   row_start = (int*)(ws + (size_t)2 * n * 4);    // n ints
    int*   bsum      = (int*)(ws + (size_t)3 * n * 4);    // 512 ints
    int*   csr       = (int*)(ws + (size_t)3 * n * 4 + 2048);            // E ints
    float* g1        = (float*)(ws + (size_t)3 * n * 4 + 2048 + (size_t)E * 4);  // 16n floats
    float* g2p       = g1 + (size_t)16 * n;                              // 4n floats
    // rank[] (E ushorts = 3.2 MB) aliases the head of g1 (6.4 MB): rank is dead
    // before k_gemm1 writes g1 (fill consumes it first; same order every replay).
    unsigned short* rank = (unsigned short*)g1;

    hipMemsetAsync(deg, 0, (size_t)n * sizeof(int), stream);

    const int B = 256;
    int gn  = (n + B - 1) / B;          // node-grid (also #scan blocks, <= 512)
    int gn4 = (4 * n + B - 1) / B;      // 4-threads-per-node grid
    int gE  = (E + B - 1) / B;          // edge-grid

    k_count_rank<<<gE, B, 0, stream>>>(dst, deg, rank, E);
    k_scan_block<<<gn, B, 0, stream>>>(deg, bsum, n);
    k_scan_top<<<1, 512, 0, stream>>>(bsum, gn);
    k_row_start<<<gn, B, 0, stream>>>(deg, bsum, row_start, dinv, n);
    k_fill<<<gE, B, 0, stream>>>(src, dst, row_start, rank, csr, E);
    k_gemm1<<<gn4, B, 0, stream>>>(x, W1, dinv, (float4*)g1, n);
    k_gather1<<<gn4, B, 0, stream>>>((const float4*)g1, csr, row_start, deg, dinv, b1, W2,
                                     (float4*)g2p, n);
    k_gather2<<<gn4, B, 0, stream>>>((const float4*)g2p, csr, row_start, deg, dinv, b2, out, n);
}